// Round 3
// baseline (986.888 us; speedup 1.0000x reference)
//
#include <hip/hip_runtime.h>
#include <cstdint>
#include <cstddef>

// Problem constants
#define NBATCH 128
#define NTIME  512
#define NIN    64
#define NHID   256
#define NG     768     // 3*H
#define NLAT   32
#define NPp    16      // P
#define NPI    48
#define NOD    8
#define NPAR   1056
#define MEAN_OFF 0
#define STD_OFF  524288      // B*T*OD
#define HT_OFF   1048576     // 2*B*T*OD

typedef _Float16 f16;
typedef _Float16 f16x2 __attribute__((ext_vector_type(2)));

static __device__ __forceinline__ f16x2 u2h(uint32_t u) {
  union { uint32_t u; f16x2 h; } x; x.u = u; return x.h;
}

static __device__ __forceinline__ float fdot2(f16x2 a, f16x2 b, float c) {
#if __has_builtin(__builtin_amdgcn_fdot2)
  return __builtin_amdgcn_fdot2(a, b, c, false);   // v_dot2_f32_f16
#else
  return c + (float)a.x * (float)b.x + (float)a.y * (float)b.y;
#endif
}
static __device__ __forceinline__ float fexp2(float x) {
#if __has_builtin(__builtin_amdgcn_exp2f)
  return __builtin_amdgcn_exp2f(x);
#else
  return exp2f(x);
#endif
}
static __device__ __forceinline__ float frcp(float x) {
#if __has_builtin(__builtin_amdgcn_rcpf)
  return __builtin_amdgcn_rcpf(x);
#else
  return 1.0f / x;
#endif
}
static __device__ __forceinline__ float fsigmoid(float x) {
  return frcp(1.0f + fexp2(-1.4426950408889634f * x));
}
static __device__ __forceinline__ float ftanh(float x) {
  return 1.0f - 2.0f * frcp(1.0f + fexp2(2.8853900817779268f * x));
}
static __device__ __forceinline__ float fexpf_(float x) {
  return fexp2(1.4426950408889634f * x);
}

// ---------------------------------------------------------------------------
// K0: one-time f32 -> f16 conversion of w_lat / w_par for the scalar path.
// ---------------------------------------------------------------------------
__global__ __launch_bounds__(256) void k_prep(
    const float* __restrict__ w_lat, const float* __restrict__ w_par,
    f16* __restrict__ w_lat16, f16* __restrict__ w_par16)
{
  const int i = blockIdx.x * 256 + threadIdx.x;
  if (i < NLAT * NHID) w_lat16[i] = (f16)w_lat[i];
  if (i < NPAR * NLAT) w_par16[i] = (f16)w_par[i];
}

// ---------------------------------------------------------------------------
// K1: gx[m, n] = sum_k x[m,k] * w_ih[n,k] + b_ih[n]   (M=65536, N=768, K=64)
// ---------------------------------------------------------------------------
__global__ __launch_bounds__(256) void k_gx(
    const float* __restrict__ x, const float* __restrict__ w_ih,
    const float* __restrict__ b_ih, f16* __restrict__ gx)
{
  __shared__ f16x2 xs[64 * 33];
  __shared__ f16x2 ws[192 * 33];
  __shared__ float bs[192];
  const int tid = threadIdx.x;
  const int m0 = blockIdx.x * 64;
  const int c0 = blockIdx.y * 192;
  const float2* x2 = (const float2*)x;
  const float2* w2 = (const float2*)w_ih;
  for (int idx = tid; idx < 64 * 32; idx += 256) {
    int r = idx >> 5, kk = idx & 31;
    float2 v = x2[(size_t)(m0 + r) * 32 + kk];
    xs[r * 33 + kk] = f16x2{(f16)v.x, (f16)v.y};
  }
  for (int idx = tid; idx < 192 * 32; idx += 256) {
    int r = idx >> 5, kk = idx & 31;
    float2 v = w2[(size_t)(c0 + r) * 32 + kk];
    ws[r * 33 + kk] = f16x2{(f16)v.x, (f16)v.y};
  }
  if (tid < 192) bs[tid] = b_ih[c0 + tid];
  __syncthreads();

  const int tc = tid & 15;
  const int tr = tid >> 4;
  float acc[4][12];
  #pragma unroll
  for (int j = 0; j < 4; ++j)
    #pragma unroll
    for (int i = 0; i < 12; ++i) acc[j][i] = 0.f;

  for (int kk = 0; kk < 32; ++kk) {
    f16x2 xa[4], wb[12];
    #pragma unroll
    for (int j = 0; j < 4; ++j) xa[j] = xs[(tr * 4 + j) * 33 + kk];
    #pragma unroll
    for (int i = 0; i < 12; ++i) wb[i] = ws[(tc * 12 + i) * 33 + kk];
    #pragma unroll
    for (int j = 0; j < 4; ++j)
      #pragma unroll
      for (int i = 0; i < 12; ++i) acc[j][i] = fdot2(xa[j], wb[i], acc[j][i]);
  }

  f16x2* g2 = (f16x2*)gx;
  #pragma unroll
  for (int j = 0; j < 4; ++j) {
    size_t row = (size_t)(m0 + tr * 4 + j);
    #pragma unroll
    for (int i2 = 0; i2 < 6; ++i2) {
      float a0 = acc[j][2 * i2]     + bs[tc * 12 + 2 * i2];
      float a1 = acc[j][2 * i2 + 1] + bs[tc * 12 + 2 * i2 + 1];
      g2[row * 384 + (size_t)(c0 / 2) + tc * 6 + i2] = f16x2{(f16)a0, (f16)a1};
    }
  }
}

// ---------------------------------------------------------------------------
// K2 v4: GRU scan. 512 threads/block, 1 batch/block, 128 blocks.
// Thread (kq = tid>>7 wave-uniform, q = tid&127) owns 6 rows {g*128+q} with
// K-slice [kq*64, kq*64+64) -> 192 f16x2 weight VGPRs (unchanged) but the
// per-step LDS h-read is 8 SAME-ADDRESS b128 broadcasts per wave (address
// independent of lane) -> minimal LDS return-BW (the v1/v3 bottleneck).
// K-reduce via stride-1 'parts' in LDS; gates on threads 0..255.
// ---------------------------------------------------------------------------
__global__ __launch_bounds__(512, 2) void k_scan(
    const float* __restrict__ hidden, const float* __restrict__ w_hh,
    const float* __restrict__ b_hh, const f16* __restrict__ gx,
    f16* __restrict__ rnn, float* __restrict__ out)
{
  __shared__ __align__(16) f16x2 hbuf[2][128];   // double-buffered h (f16)
  __shared__ float parts[4 * 768];               // [kq][row] partial sums
  const int tid = threadIdx.x;
  const int b = blockIdx.x;
  const int kq = tid >> 7;       // 0..3, wave-uniform
  const int q  = tid & 127;

  // --- stationary weights: rows g*128+q (g=0..5), k in [kq*64, kq*64+64)
  f16x2 w[6][32];
  const float2* wh2 = (const float2*)w_hh;   // 128 float2 per row
  #pragma unroll
  for (int g = 0; g < 6; ++g) {
    const int row = g * 128 + q;
    #pragma unroll
    for (int c = 0; c < 32; ++c) {
      float2 v = wh2[(size_t)row * 128 + kq * 32 + c];
      w[g][c] = f16x2{(f16)v.x, (f16)v.y};
    }
  }

  // --- gate-thread state (tid < 256 owns unit u = tid)
  float br = 0.f, bz = 0.f, bn = 0.f, hprev = 0.f;
  f16 c_r = 0, c_z = 0, c_n = 0, p_r = 0, p_z = 0, p_n = 0;
  const f16* gp = gx + (size_t)b * NTIME * NG;
  if (tid < 256) {
    br = b_hh[tid]; bz = b_hh[256 + tid]; bn = b_hh[512 + tid];
    hprev = hidden[b * 256 + tid];
    ((f16*)hbuf[0])[tid] = (f16)hprev;
    c_r = gp[tid];      c_z = gp[256 + tid];      c_n = gp[512 + tid];
    p_r = gp[NG + tid]; p_z = gp[NG + 256 + tid]; p_n = gp[NG + 512 + tid];
  }
  f16* rnn_p = rnn + (size_t)b * NTIME * NHID + tid;   // used only if tid<256
  __syncthreads();

  for (int t = 0; t < NTIME; ++t) {
    // issue gx prefetch for t+2 early (hides under the dot phase)
    f16 q_r = 0, q_z = 0, q_n = 0;
    if (tid < 256) {
      const int tp = (t + 2 < NTIME) ? (t + 2) : (NTIME - 1);
      const f16* gq = gp + (size_t)tp * NG;
      q_r = gq[tid]; q_z = gq[256 + tid]; q_n = gq[512 + tid];
    }

    // --- phase A: 192 dot2 per thread; h via same-address b128 broadcasts
    const uint4* hb = (const uint4*)(&hbuf[t & 1][kq * 32]);
    float a0 = 0.f, a1 = 0.f, a2 = 0.f, a3 = 0.f, a4 = 0.f, a5 = 0.f;
    #pragma unroll
    for (int c4 = 0; c4 < 8; ++c4) {
      uint4 hv = hb[c4];                        // uniform addr across wave
      f16x2 h0 = u2h(hv.x), h1 = u2h(hv.y), h2v = u2h(hv.z), h3 = u2h(hv.w);
      a0 = fdot2(w[0][c4 * 4 + 0], h0, a0);
      a1 = fdot2(w[1][c4 * 4 + 0], h0, a1);
      a2 = fdot2(w[2][c4 * 4 + 0], h0, a2);
      a3 = fdot2(w[3][c4 * 4 + 0], h0, a3);
      a4 = fdot2(w[4][c4 * 4 + 0], h0, a4);
      a5 = fdot2(w[5][c4 * 4 + 0], h0, a5);
      a0 = fdot2(w[0][c4 * 4 + 1], h1, a0);
      a1 = fdot2(w[1][c4 * 4 + 1], h1, a1);
      a2 = fdot2(w[2][c4 * 4 + 1], h1, a2);
      a3 = fdot2(w[3][c4 * 4 + 1], h1, a3);
      a4 = fdot2(w[4][c4 * 4 + 1], h1, a4);
      a5 = fdot2(w[5][c4 * 4 + 1], h1, a5);
      a0 = fdot2(w[0][c4 * 4 + 2], h2v, a0);
      a1 = fdot2(w[1][c4 * 4 + 2], h2v, a1);
      a2 = fdot2(w[2][c4 * 4 + 2], h2v, a2);
      a3 = fdot2(w[3][c4 * 4 + 2], h2v, a3);
      a4 = fdot2(w[4][c4 * 4 + 2], h2v, a4);
      a5 = fdot2(w[5][c4 * 4 + 2], h2v, a5);
      a0 = fdot2(w[0][c4 * 4 + 3], h3, a0);
      a1 = fdot2(w[1][c4 * 4 + 3], h3, a1);
      a2 = fdot2(w[2][c4 * 4 + 3], h3, a2);
      a3 = fdot2(w[3][c4 * 4 + 3], h3, a3);
      a4 = fdot2(w[4][c4 * 4 + 3], h3, a4);
      a5 = fdot2(w[5][c4 * 4 + 3], h3, a5);
    }
    {
      float* pp = parts + kq * 768 + q;   // stride-1 across lanes
      pp[0]   = a0; pp[128] = a1; pp[256] = a2;
      pp[384] = a3; pp[512] = a4; pp[640] = a5;
    }
    __syncthreads();

    // --- phase B: gates on threads 0..255
    if (tid < 256) {
      const int u = tid;
      float gr = br + (float)c_r;
      float gz = bz + (float)c_z;
      float hn = bn;
      #pragma unroll
      for (int kk = 0; kk < 4; ++kk) {
        gr += parts[kk * 768 + u];
        gz += parts[kk * 768 + 256 + u];
        hn += parts[kk * 768 + 512 + u];
      }
      float r_ = fsigmoid(gr);
      float z_ = fsigmoid(gz);
      float n_ = ftanh((float)c_n + r_ * hn);
      hprev = (1.0f - z_) * n_ + z_ * hprev;
      ((f16*)hbuf[(t + 1) & 1])[u] = (f16)hprev;
      rnn_p[(size_t)t * NHID] = (f16)hprev;
      c_r = p_r; c_z = p_z; c_n = p_n;
      p_r = q_r; p_z = q_z; p_n = q_n;
    }
    __syncthreads();
  }
  if (tid < 256) out[HT_OFF + b * 256 + tid] = hprev;
}

// ---------------------------------------------------------------------------
// K3 helper: 32-wide dot of one w_par row (f16 in GLOBAL, uniform index ->
// scalar s_load path) against te2 (f16 pairs in regs), fp32 accum.
// ---------------------------------------------------------------------------
static __device__ __forceinline__ float rowdot(const uint4* __restrict__ w4,
                                               const f16x2 te2[16],
                                               float init, int row)
{
  const uint4* p = w4 + row * 4;
  float a0 = init, a1 = 0.f, a2 = 0.f, a3 = 0.f;
  #pragma unroll
  for (int c4 = 0; c4 < 4; ++c4) {
    uint4 v = p[c4];
    a0 = fdot2(u2h(v.x), te2[4 * c4 + 0], a0);
    a1 = fdot2(u2h(v.y), te2[4 * c4 + 1], a1);
    a2 = fdot2(u2h(v.z), te2[4 * c4 + 2], a2);
    a3 = fdot2(u2h(v.w), te2[4 * c4 + 3], a3);
  }
  return (a0 + a1) + (a2 + a3);
}

// ---------------------------------------------------------------------------
// K3 v2: head, LDS-free. All weight/bias reads have wave-uniform addresses ->
// scalar cache (s_load), no LDS staging, no barriers. 512 blocks x 128 thr.
// ---------------------------------------------------------------------------
#define HEAD_T 128
__global__ __launch_bounds__(HEAD_T) void k_head(
    const float* __restrict__ x, const f16* __restrict__ w_lat16,
    const float* __restrict__ b_lat, const f16* __restrict__ w_par16,
    const float* __restrict__ b_par, const f16* __restrict__ rnn,
    float* __restrict__ out)
{
  const int tid = threadIdx.x;
  const size_t m = (size_t)blockIdx.x * HEAD_T + tid;

  // te = b_lat + w_lat @ h   (w_lat rows: 128 f16 pairs each, uniform reads)
  float te[32];
  #pragma unroll
  for (int c = 0; c < 32; ++c) te[c] = b_lat[c];
  const uint4* hrow = (const uint4*)(rnn + m * NHID);
  const uint4* wl4 = (const uint4*)w_lat16;    // 32 uint4 per row
  #pragma unroll 4
  for (int c4 = 0; c4 < 32; ++c4) {
    uint4 hv = hrow[c4];
    f16x2 hx0 = u2h(hv.x), hx1 = u2h(hv.y), hx2 = u2h(hv.z), hx3 = u2h(hv.w);
    #pragma unroll
    for (int c = 0; c < 32; ++c) {
      uint4 wv = wl4[c * 32 + c4];             // uniform -> s_load
      te[c] = fdot2(u2h(wv.x), hx0, te[c]);
      te[c] = fdot2(u2h(wv.y), hx1, te[c]);
      te[c] = fdot2(u2h(wv.z), hx2, te[c]);
      te[c] = fdot2(u2h(wv.w), hx3, te[c]);
    }
  }
  f16x2 te2[16];
  #pragma unroll
  for (int k = 0; k < 16; ++k) te2[k] = f16x2{(f16)te[2 * k], (f16)te[2 * k + 1]};

  const uint4* wp4 = (const uint4*)w_par16;    // 4 uint4 per row

  // hyper-layer 1: w_h rows [0,768), b_h rows [768,784)
  float vh[16];
  #pragma unroll
  for (int p = 0; p < 16; ++p) vh[p] = 0.f;
  for (int i = 0; i < NPI; ++i) {
    float xi = x[m * NIN + i];
    #pragma unroll
    for (int p = 0; p < 16; ++p) {
      int row = p * NPI + i;
      float wv = rowdot(wp4, te2, b_par[row], row);
      vh[p] += wv * xi;
    }
  }
  float oh[16];
  #pragma unroll
  for (int p = 0; p < 16; ++p) {
    float bh = rowdot(wp4, te2, b_par[768 + p], 768 + p);
    oh[p] = ftanh(vh[p] + bh);
  }

  // hyper-layer 2: w_o rows [784,1040), b_o rows [1040,1056)
  for (int o = 0; o < 16; ++o) {
    float macc = rowdot(wp4, te2, b_par[1040 + o], 1040 + o);
    #pragma unroll
    for (int p = 0; p < 16; ++p) {
      int row = 784 + o * 16 + p;
      float wv = rowdot(wp4, te2, b_par[row], row);
      macc += wv * oh[p];
    }
    if (o < NOD) out[MEAN_OFF + m * NOD + o] = macc;
    else         out[STD_OFF + m * NOD + (o - NOD)] = fexpf_(macc);
  }
}

// ---------------------------------------------------------------------------
extern "C" void kernel_launch(void* const* d_in, const int* in_sizes, int n_in,
                              void* d_out, int out_size, void* d_ws, size_t ws_size,
                              hipStream_t stream)
{
  const float* x      = (const float*)d_in[0];
  const float* hidden = (const float*)d_in[1];
  const float* w_ih   = (const float*)d_in[2];
  const float* w_hh   = (const float*)d_in[3];
  const float* b_ih   = (const float*)d_in[4];
  const float* b_hh   = (const float*)d_in[5];
  const float* w_lat  = (const float*)d_in[6];
  const float* b_lat  = (const float*)d_in[7];
  const float* w_par  = (const float*)d_in[8];
  const float* b_par  = (const float*)d_in[9];
  float* out = (float*)d_out;

  f16* gx      = (f16*)d_ws;                                  // 100,663,296 B
  f16* rnn     = (f16*)((char*)d_ws + 100663296);             // 33,554,432 B
  f16* w_lat16 = (f16*)((char*)d_ws + 134217728);             // 16,384 B
  f16* w_par16 = (f16*)((char*)d_ws + 134234112);             // 67,584 B

  k_prep<<<132, 256, 0, stream>>>(w_lat, w_par, w_lat16, w_par16);
  k_gx  <<<dim3(1024, 4), 256, 0, stream>>>(x, w_ih, b_ih, gx);
  k_scan<<<NBATCH, 512, 0, stream>>>(hidden, w_hh, b_hh, gx, rnn, out);
  k_head<<<512, HEAD_T, 0, stream>>>(x, w_lat16, b_lat, w_par16, b_par, rnn, out);
}

// Round 4
// 884.514 us; speedup vs baseline: 1.1157x; 1.1157x over previous
//
#include <hip/hip_runtime.h>
#include <cstdint>
#include <cstddef>

// Problem constants
#define NBATCH 128
#define NTIME  512
#define NIN    64
#define NHID   256
#define NG     768     // 3*H
#define NLAT   32
#define NPp    16      // P
#define NPI    48
#define NOD    8
#define NPAR   1056
#define MEAN_OFF 0
#define STD_OFF  524288      // B*T*OD
#define HT_OFF   1048576     // 2*B*T*OD

typedef _Float16 f16;
typedef _Float16 f16x2 __attribute__((ext_vector_type(2)));

static __device__ __forceinline__ f16x2 u2h(uint32_t u) {
  union { uint32_t u; f16x2 h; } x; x.u = u; return x.h;
}

static __device__ __forceinline__ float fdot2(f16x2 a, f16x2 b, float c) {
#if __has_builtin(__builtin_amdgcn_fdot2)
  return __builtin_amdgcn_fdot2(a, b, c, false);   // v_dot2_f32_f16
#else
  return c + (float)a.x * (float)b.x + (float)a.y * (float)b.y;
#endif
}
static __device__ __forceinline__ float fexp2(float x) {
#if __has_builtin(__builtin_amdgcn_exp2f)
  return __builtin_amdgcn_exp2f(x);
#else
  return exp2f(x);
#endif
}
static __device__ __forceinline__ float frcp(float x) {
#if __has_builtin(__builtin_amdgcn_rcpf)
  return __builtin_amdgcn_rcpf(x);
#else
  return 1.0f / x;
#endif
}
static __device__ __forceinline__ float fsigmoid(float x) {
  return frcp(1.0f + fexp2(-1.4426950408889634f * x));
}
static __device__ __forceinline__ float ftanh(float x) {
  return 1.0f - 2.0f * frcp(1.0f + fexp2(2.8853900817779268f * x));
}
static __device__ __forceinline__ float fexpf_(float x) {
  return fexp2(1.4426950408889634f * x);
}

// ---------------------------------------------------------------------------
// K1: gx[m, n] = sum_k x[m,k] * w_ih[n,k] + b_ih[n]   (M=65536, N=768, K=64)
// ---------------------------------------------------------------------------
__global__ __launch_bounds__(256) void k_gx(
    const float* __restrict__ x, const float* __restrict__ w_ih,
    const float* __restrict__ b_ih, f16* __restrict__ gx)
{
  __shared__ f16x2 xs[64 * 33];
  __shared__ f16x2 ws[192 * 33];
  __shared__ float bs[192];
  const int tid = threadIdx.x;
  const int m0 = blockIdx.x * 64;
  const int c0 = blockIdx.y * 192;
  const float2* x2 = (const float2*)x;
  const float2* w2 = (const float2*)w_ih;
  for (int idx = tid; idx < 64 * 32; idx += 256) {
    int r = idx >> 5, kk = idx & 31;
    float2 v = x2[(size_t)(m0 + r) * 32 + kk];
    xs[r * 33 + kk] = f16x2{(f16)v.x, (f16)v.y};
  }
  for (int idx = tid; idx < 192 * 32; idx += 256) {
    int r = idx >> 5, kk = idx & 31;
    float2 v = w2[(size_t)(c0 + r) * 32 + kk];
    ws[r * 33 + kk] = f16x2{(f16)v.x, (f16)v.y};
  }
  if (tid < 192) bs[tid] = b_ih[c0 + tid];
  __syncthreads();

  const int tc = tid & 15;
  const int tr = tid >> 4;
  float acc[4][12];
  #pragma unroll
  for (int j = 0; j < 4; ++j)
    #pragma unroll
    for (int i = 0; i < 12; ++i) acc[j][i] = 0.f;

  for (int kk = 0; kk < 32; ++kk) {
    f16x2 xa[4], wb[12];
    #pragma unroll
    for (int j = 0; j < 4; ++j) xa[j] = xs[(tr * 4 + j) * 33 + kk];
    #pragma unroll
    for (int i = 0; i < 12; ++i) wb[i] = ws[(tc * 12 + i) * 33 + kk];
    #pragma unroll
    for (int j = 0; j < 4; ++j)
      #pragma unroll
      for (int i = 0; i < 12; ++i) acc[j][i] = fdot2(xa[j], wb[i], acc[j][i]);
  }

  f16x2* g2 = (f16x2*)gx;
  #pragma unroll
  for (int j = 0; j < 4; ++j) {
    size_t row = (size_t)(m0 + tr * 4 + j);
    #pragma unroll
    for (int i2 = 0; i2 < 6; ++i2) {
      float a0 = acc[j][2 * i2]     + bs[tc * 12 + 2 * i2];
      float a1 = acc[j][2 * i2 + 1] + bs[tc * 12 + 2 * i2 + 1];
      g2[row * 384 + (size_t)(c0 / 2) + tc * 6 + i2] = f16x2{(f16)a0, (f16)a1};
    }
  }
}

// ---------------------------------------------------------------------------
// K2 v5: GRU scan. Same structure as v4 (conflict-free), but the weight
// arrays are FORCED into VGPRs: amdgpu_waves_per_eu(2,2) pins the register
// budget to 256/thread (launch_bounds(512,2) alone left the allocator at a
// 128-reg / 4-wave target -> 192-reg weight array spilled to scratch ->
// every version hit the same ~620 us scratch-BW wall). Six 32-element
// arrays (128 B each) for reliable SROA promotion.
// ---------------------------------------------------------------------------
__global__
__attribute__((amdgpu_flat_work_group_size(512, 512)))
__attribute__((amdgpu_waves_per_eu(2, 2)))
void k_scan(
    const float* __restrict__ hidden, const float* __restrict__ w_hh,
    const float* __restrict__ b_hh, const f16* __restrict__ gx,
    f16* __restrict__ rnn, float* __restrict__ out)
{
  __shared__ __align__(16) f16x2 hbuf[2][128];   // double-buffered h (f16)
  __shared__ float parts[4 * 768];               // [kq][row] partial sums
  const int tid = threadIdx.x;
  const int b = blockIdx.x;
  const int kq = tid >> 7;       // 0..3, wave-uniform
  const int q  = tid & 127;

  // --- stationary weights: rows g*128+q (g=0..5), k in [kq*64, kq*64+64)
  f16x2 w0[32], w1[32], w2[32], w3[32], w4[32], w5[32];
  const float2* wh2 = (const float2*)w_hh;   // 128 float2 per row
  #pragma unroll
  for (int c = 0; c < 32; ++c) {
    float2 v;
    v = wh2[(size_t)(0 * 128 + q) * 128 + kq * 32 + c]; w0[c] = f16x2{(f16)v.x, (f16)v.y};
    v = wh2[(size_t)(1 * 128 + q) * 128 + kq * 32 + c]; w1[c] = f16x2{(f16)v.x, (f16)v.y};
    v = wh2[(size_t)(2 * 128 + q) * 128 + kq * 32 + c]; w2[c] = f16x2{(f16)v.x, (f16)v.y};
    v = wh2[(size_t)(3 * 128 + q) * 128 + kq * 32 + c]; w3[c] = f16x2{(f16)v.x, (f16)v.y};
    v = wh2[(size_t)(4 * 128 + q) * 128 + kq * 32 + c]; w4[c] = f16x2{(f16)v.x, (f16)v.y};
    v = wh2[(size_t)(5 * 128 + q) * 128 + kq * 32 + c]; w5[c] = f16x2{(f16)v.x, (f16)v.y};
  }

  // --- gate-thread state (tid < 256 owns unit u = tid)
  float br = 0.f, bz = 0.f, bn = 0.f, hprev = 0.f;
  f16 c_r = 0, c_z = 0, c_n = 0, p_r = 0, p_z = 0, p_n = 0;
  const f16* gp = gx + (size_t)b * NTIME * NG;
  if (tid < 256) {
    br = b_hh[tid]; bz = b_hh[256 + tid]; bn = b_hh[512 + tid];
    hprev = hidden[b * 256 + tid];
    ((f16*)hbuf[0])[tid] = (f16)hprev;
    c_r = gp[tid];      c_z = gp[256 + tid];      c_n = gp[512 + tid];
    p_r = gp[NG + tid]; p_z = gp[NG + 256 + tid]; p_n = gp[NG + 512 + tid];
  }
  f16* rnn_p = rnn + (size_t)b * NTIME * NHID + tid;   // used only if tid<256
  __syncthreads();

  for (int t = 0; t < NTIME; ++t) {
    // issue gx prefetch for t+2 early (hides under the dot phase)
    f16 q_r = 0, q_z = 0, q_n = 0;
    if (tid < 256) {
      const int tp = (t + 2 < NTIME) ? (t + 2) : (NTIME - 1);
      const f16* gq = gp + (size_t)tp * NG;
      q_r = gq[tid]; q_z = gq[256 + tid]; q_n = gq[512 + tid];
    }

    // --- phase A: 192 dot2 per thread; h via same-address b128 broadcasts
    const uint4* hb = (const uint4*)(&hbuf[t & 1][kq * 32]);
    float a0 = 0.f, a1 = 0.f, a2 = 0.f, a3 = 0.f, a4 = 0.f, a5 = 0.f;
    #pragma unroll
    for (int c4 = 0; c4 < 8; ++c4) {
      uint4 hv = hb[c4];                        // uniform addr across wave
      f16x2 h0 = u2h(hv.x), h1 = u2h(hv.y), h2v = u2h(hv.z), h3 = u2h(hv.w);
      a0 = fdot2(w0[c4 * 4 + 0], h0, a0);
      a1 = fdot2(w1[c4 * 4 + 0], h0, a1);
      a2 = fdot2(w2[c4 * 4 + 0], h0, a2);
      a3 = fdot2(w3[c4 * 4 + 0], h0, a3);
      a4 = fdot2(w4[c4 * 4 + 0], h0, a4);
      a5 = fdot2(w5[c4 * 4 + 0], h0, a5);
      a0 = fdot2(w0[c4 * 4 + 1], h1, a0);
      a1 = fdot2(w1[c4 * 4 + 1], h1, a1);
      a2 = fdot2(w2[c4 * 4 + 1], h1, a2);
      a3 = fdot2(w3[c4 * 4 + 1], h1, a3);
      a4 = fdot2(w4[c4 * 4 + 1], h1, a4);
      a5 = fdot2(w5[c4 * 4 + 1], h1, a5);
      a0 = fdot2(w0[c4 * 4 + 2], h2v, a0);
      a1 = fdot2(w1[c4 * 4 + 2], h2v, a1);
      a2 = fdot2(w2[c4 * 4 + 2], h2v, a2);
      a3 = fdot2(w3[c4 * 4 + 2], h2v, a3);
      a4 = fdot2(w4[c4 * 4 + 2], h2v, a4);
      a5 = fdot2(w5[c4 * 4 + 2], h2v, a5);
      a0 = fdot2(w0[c4 * 4 + 3], h3, a0);
      a1 = fdot2(w1[c4 * 4 + 3], h3, a1);
      a2 = fdot2(w2[c4 * 4 + 3], h3, a2);
      a3 = fdot2(w3[c4 * 4 + 3], h3, a3);
      a4 = fdot2(w4[c4 * 4 + 3], h3, a4);
      a5 = fdot2(w5[c4 * 4 + 3], h3, a5);
    }
    {
      float* pp = parts + kq * 768 + q;   // stride-1 across lanes
      pp[0]   = a0; pp[128] = a1; pp[256] = a2;
      pp[384] = a3; pp[512] = a4; pp[640] = a5;
    }
    __syncthreads();

    // --- phase B: gates on threads 0..255
    if (tid < 256) {
      const int u = tid;
      float gr = br + (float)c_r;
      float gz = bz + (float)c_z;
      float hn = bn;
      #pragma unroll
      for (int kk = 0; kk < 4; ++kk) {
        gr += parts[kk * 768 + u];
        gz += parts[kk * 768 + 256 + u];
        hn += parts[kk * 768 + 512 + u];
      }
      float r_ = fsigmoid(gr);
      float z_ = fsigmoid(gz);
      float n_ = ftanh((float)c_n + r_ * hn);
      hprev = (1.0f - z_) * n_ + z_ * hprev;
      ((f16*)hbuf[(t + 1) & 1])[u] = (f16)hprev;
      rnn_p[(size_t)t * NHID] = (f16)hprev;
      c_r = p_r; c_z = p_z; c_n = p_n;
      p_r = q_r; p_z = q_z; p_n = q_n;
    }
    __syncthreads();
  }
  if (tid < 256) out[HT_OFF + b * 256 + tid] = hprev;
}

// ---------------------------------------------------------------------------
// K3 helper: half-row dot (16 of 32 latents; caller pre-offset wb by kh*2
// uint4 and t8 = te2 + kh*8). init carries b_par[row] on kh==0 only.
// ---------------------------------------------------------------------------
static __device__ __forceinline__ float rowdot_h(const uint4* __restrict__ wb,
                                                 const f16x2* __restrict__ t8,
                                                 int r, float init)
{
  uint4 v0 = wb[r * 4];
  uint4 v1 = wb[r * 4 + 1];
  float a0 = init, a1 = 0.f, a2 = 0.f, a3 = 0.f;
  a0 = fdot2(u2h(v0.x), t8[0], a0);
  a1 = fdot2(u2h(v0.y), t8[1], a1);
  a2 = fdot2(u2h(v0.z), t8[2], a2);
  a3 = fdot2(u2h(v0.w), t8[3], a3);
  a0 = fdot2(u2h(v1.x), t8[4], a0);
  a1 = fdot2(u2h(v1.y), t8[5], a1);
  a2 = fdot2(u2h(v1.z), t8[6], a2);
  a3 = fdot2(u2h(v1.w), t8[7], a3);
  return (a0 + a1) + (a2 + a3);
}

// ---------------------------------------------------------------------------
// K3 v3: head, 2 threads per (b,t) row (kh = K-half) -> 2048 waves = 2/SIMD
// (one-row-per-thread caps at 1 wave/SIMD GPU-wide: latency-bound).
// All linear partial sums stay split per-half; combine via shfl_xor(1) only
// at nonlinearities. LDS staged in <=24 KB chunks.
// ---------------------------------------------------------------------------
#define HEAD_T 256
__global__ __launch_bounds__(HEAD_T) void k_head(
    const float* __restrict__ x, const float* __restrict__ w_lat,
    const float* __restrict__ b_lat, const float* __restrict__ w_par,
    const float* __restrict__ b_par, const f16* __restrict__ rnn,
    float* __restrict__ out)
{
  __shared__ __align__(16) f16x2 buf[384 * 16];   // 24 KB chunk buffer
  const int tid = threadIdx.x;
  const int j = tid >> 1, kh = tid & 1;
  const size_t m = (size_t)blockIdx.x * (HEAD_T / 2) + j;

  // ---- phase A: te = b_lat + w_lat @ h  (K split by kh)
  const float2* wl2 = (const float2*)w_lat;
  for (int idx = tid; idx < 32 * 128; idx += HEAD_T) {
    float2 v = wl2[idx];
    buf[idx] = f16x2{(f16)v.x, (f16)v.y};
  }
  __syncthreads();

  float te[32];
  #pragma unroll
  for (int c = 0; c < 32; ++c) te[c] = kh ? 0.f : b_lat[c];
  const uint4* hrow = (const uint4*)(rnn + m * NHID) + kh * 16;
  const uint4* wl4 = (const uint4*)buf;    // 32 uint4 per 256-wide row
  #pragma unroll 2
  for (int c4 = 0; c4 < 16; ++c4) {
    uint4 hv = hrow[c4];
    f16x2 hx0 = u2h(hv.x), hx1 = u2h(hv.y), hx2 = u2h(hv.z), hx3 = u2h(hv.w);
    #pragma unroll
    for (int c = 0; c < 32; ++c) {
      uint4 wv = wl4[c * 32 + kh * 16 + c4];
      te[c] = fdot2(u2h(wv.x), hx0, te[c]);
      te[c] = fdot2(u2h(wv.y), hx1, te[c]);
      te[c] = fdot2(u2h(wv.z), hx2, te[c]);
      te[c] = fdot2(u2h(wv.w), hx3, te[c]);
    }
  }
  #pragma unroll
  for (int c = 0; c < 32; ++c) te[c] += __shfl_xor(te[c], 1, 64);
  f16x2 te2[16];
  #pragma unroll
  for (int k = 0; k < 16; ++k) te2[k] = f16x2{(f16)te[2 * k], (f16)te[2 * k + 1]};
  const f16x2* t8 = te2 + kh * 8;
  __syncthreads();

  const float2* wp2 = (const float2*)w_par;   // 16 float2 per 32-wide row
  const uint4* wb = ((const uint4*)buf) + kh * 2;
  const float* xrow = x + m * NIN;
  float vh[16];
  #pragma unroll
  for (int p = 0; p < 16; ++p) vh[p] = 0.f;

  // ---- phase B0: w_h rows [0,384)  (p = 0..7)
  for (int idx = tid; idx < 384 * 16; idx += HEAD_T) {
    float2 v = wp2[idx];
    buf[idx] = f16x2{(f16)v.x, (f16)v.y};
  }
  __syncthreads();
  for (int i = 0; i < NPI; ++i) {
    float xi = xrow[i];
    #pragma unroll
    for (int p = 0; p < 8; ++p) {
      int row = p * NPI + i;
      float wv = rowdot_h(wb, t8, row, kh ? 0.f : b_par[row]);
      vh[p] += wv * xi;
    }
  }
  __syncthreads();

  // ---- phase B1: w_h rows [384,768)  (p = 8..15)
  for (int idx = tid; idx < 384 * 16; idx += HEAD_T) {
    float2 v = wp2[384 * 16 + idx];
    buf[idx] = f16x2{(f16)v.x, (f16)v.y};
  }
  __syncthreads();
  for (int i = 0; i < NPI; ++i) {
    float xi = xrow[i];
    #pragma unroll
    for (int p = 8; p < 16; ++p) {
      int row = p * NPI + i;
      float wv = rowdot_h(wb, t8, row - 384, kh ? 0.f : b_par[row]);
      vh[p] += wv * xi;
    }
  }
  __syncthreads();

  // ---- phase C: rows [768,1056) = b_h(16) + w_o(256) + b_o(16), 18 KB
  for (int idx = tid; idx < 288 * 16; idx += HEAD_T) {
    float2 v = wp2[768 * 16 + idx];
    buf[idx] = f16x2{(f16)v.x, (f16)v.y};
  }
  __syncthreads();

  float oh[16];
  #pragma unroll
  for (int p = 0; p < 16; ++p) {
    float bh = rowdot_h(wb, t8, p, kh ? 0.f : b_par[768 + p]);   // local row p
    float s = vh[p] + bh;
    s += __shfl_xor(s, 1, 64);
    oh[p] = ftanh(s);
  }

  #pragma unroll 2
  for (int o = 0; o < 16; ++o) {
    // b_o: local rows 272..288
    float macc = rowdot_h(wb, t8, 272 + o, kh ? 0.f : b_par[1040 + o]);
    #pragma unroll
    for (int p = 0; p < 16; ++p) {
      int grow = 784 + o * 16 + p;           // local 16 + o*16 + p
      float wv = rowdot_h(wb, t8, 16 + o * 16 + p, kh ? 0.f : b_par[grow]);
      macc += wv * oh[p];
    }
    macc += __shfl_xor(macc, 1, 64);
    if (!kh) {
      if (o < NOD) out[MEAN_OFF + m * NOD + o] = macc;
      else         out[STD_OFF + m * NOD + (o - NOD)] = fexpf_(macc);
    }
  }
}

// ---------------------------------------------------------------------------
extern "C" void kernel_launch(void* const* d_in, const int* in_sizes, int n_in,
                              void* d_out, int out_size, void* d_ws, size_t ws_size,
                              hipStream_t stream)
{
  const float* x      = (const float*)d_in[0];
  const float* hidden = (const float*)d_in[1];
  const float* w_ih   = (const float*)d_in[2];
  const float* w_hh   = (const float*)d_in[3];
  const float* b_ih   = (const float*)d_in[4];
  const float* b_hh   = (const float*)d_in[5];
  const float* w_lat  = (const float*)d_in[6];
  const float* b_lat  = (const float*)d_in[7];
  const float* w_par  = (const float*)d_in[8];
  const float* b_par  = (const float*)d_in[9];
  float* out = (float*)d_out;

  f16* gx  = (f16*)d_ws;                                  // 100,663,296 B
  f16* rnn = (f16*)((char*)d_ws + 100663296);             // 33,554,432 B

  k_gx  <<<dim3(1024, 4), 256, 0, stream>>>(x, w_ih, b_ih, gx);
  k_scan<<<NBATCH, 512, 0, stream>>>(hidden, w_hh, b_hh, gx, rnn, out);
  k_head<<<512, HEAD_T, 0, stream>>>(x, w_lat, b_lat, w_par, b_par, rnn, out);
}